// Round 1
// baseline (760.328 us; speedup 1.0000x reference)
//
#include <hip/hip_runtime.h>
#include <math.h>

// GraphAttentionBlock: B=1, N=4096, E=256, H=8, D=32, fp32 in/out.
// R1: correct fp32 baseline. qkv GEMM -> flash attention w/ adjacency mask ->
// out GEMM. Workspace: q/k/v head-major [H][N][32] + attn [N][256] = 16 MB.

#define NTOK 4096
#define EDIM 256
#define HEADS 8
#define HD 32
#define QSCALE 0.17677669529663687f  // 1/sqrt(32)

// ---------------- QKV projection: Y = X @ W^T + b, head-major out ----------
__global__ __launch_bounds__(256) void qkv_gemm(
    const float* __restrict__ x,
    const float* __restrict__ Wq, const float* __restrict__ bq,
    const float* __restrict__ Wk, const float* __restrict__ bk,
    const float* __restrict__ Wv, const float* __restrict__ bv,
    float* __restrict__ qo, float* __restrict__ ko, float* __restrict__ vo)
{
    const int wsel = blockIdx.y >> 2;           // 0=Q 1=K 2=V
    const int n0 = (blockIdx.y & 3) << 6;       // output-feature tile
    const int m0 = blockIdx.x << 6;             // token tile
    const float* __restrict__ W    = (wsel == 0) ? Wq : (wsel == 1) ? Wk : Wv;
    const float* __restrict__ bias = (wsel == 0) ? bq : (wsel == 1) ? bk : bv;
    float* __restrict__ out        = (wsel == 0) ? qo : (wsel == 1) ? ko : vo;

    __shared__ float Xs[64][17];   // +1 pad breaks bank aliasing
    __shared__ float Wt[64][17];

    const int tid = threadIdx.x;
    const int tx = tid & 15, ty = tid >> 4;
    const int lr = tid >> 2, lc = (tid & 3) << 2;

    float acc[4][4] = {};
    for (int k0 = 0; k0 < 256; k0 += 16) {
        float4 xv = *(const float4*)&x[(m0 + lr) * 256 + k0 + lc];
        float4 wv = *(const float4*)&W[(n0 + lr) * 256 + k0 + lc];
        Xs[lr][lc + 0] = xv.x; Xs[lr][lc + 1] = xv.y;
        Xs[lr][lc + 2] = xv.z; Xs[lr][lc + 3] = xv.w;
        Wt[lr][lc + 0] = wv.x; Wt[lr][lc + 1] = wv.y;
        Wt[lr][lc + 2] = wv.z; Wt[lr][lc + 3] = wv.w;
        __syncthreads();
#pragma unroll
        for (int kk = 0; kk < 16; ++kk) {
            float a0 = Xs[ty * 4 + 0][kk], a1 = Xs[ty * 4 + 1][kk];
            float a2 = Xs[ty * 4 + 2][kk], a3 = Xs[ty * 4 + 3][kk];
            float b0 = Wt[tx * 4 + 0][kk], b1 = Wt[tx * 4 + 1][kk];
            float b2 = Wt[tx * 4 + 2][kk], b3 = Wt[tx * 4 + 3][kk];
            acc[0][0] = fmaf(a0, b0, acc[0][0]); acc[0][1] = fmaf(a0, b1, acc[0][1]);
            acc[0][2] = fmaf(a0, b2, acc[0][2]); acc[0][3] = fmaf(a0, b3, acc[0][3]);
            acc[1][0] = fmaf(a1, b0, acc[1][0]); acc[1][1] = fmaf(a1, b1, acc[1][1]);
            acc[1][2] = fmaf(a1, b2, acc[1][2]); acc[1][3] = fmaf(a1, b3, acc[1][3]);
            acc[2][0] = fmaf(a2, b0, acc[2][0]); acc[2][1] = fmaf(a2, b1, acc[2][1]);
            acc[2][2] = fmaf(a2, b2, acc[2][2]); acc[2][3] = fmaf(a2, b3, acc[2][3]);
            acc[3][0] = fmaf(a3, b0, acc[3][0]); acc[3][1] = fmaf(a3, b1, acc[3][1]);
            acc[3][2] = fmaf(a3, b2, acc[3][2]); acc[3][3] = fmaf(a3, b3, acc[3][3]);
        }
        __syncthreads();
    }
    const int e0 = n0 + tx * 4;
    const float b0 = bias[e0 + 0], b1 = bias[e0 + 1];
    const float b2 = bias[e0 + 2], b3 = bias[e0 + 3];
    const int h = e0 >> 5, d0 = e0 & 31;   // 4 contiguous features stay in one head
#pragma unroll
    for (int i = 0; i < 4; ++i) {
        const int row = m0 + ty * 4 + i;
        float4 r;
        r.x = acc[i][0] + b0; r.y = acc[i][1] + b1;
        r.z = acc[i][2] + b2; r.w = acc[i][3] + b3;
        *(float4*)&out[h * (NTOK * HD) + row * HD + d0] = r;
    }
}

// ---------------- flash attention with adjacency mask ----------------------
__global__ __launch_bounds__(256) void attn_kernel(
    const float* __restrict__ qg, const float* __restrict__ kg,
    const float* __restrict__ vg, const int* __restrict__ adj,
    float* __restrict__ attn_out)
{
    const int h = blockIdx.y;
    const int q0 = blockIdx.x << 6;
    const float* __restrict__ Q = qg + h * (NTOK * HD);
    const float* __restrict__ K = kg + h * (NTOK * HD);
    const float* __restrict__ V = vg + h * (NTOK * HD);

    __shared__ float Qs[64][32];     // broadcast reads -> no pad needed
    __shared__ float KsT[32][65];    // transposed, +1 pad
    __shared__ float Vs[64][32];     // float4 PV reads, conflict-free
    __shared__ float Ss[64][65];     // scores/probs, +1 pad
    __shared__ float mrow[64], lrow[64], arow[64];
    __shared__ float red[64][4];

    const int tid = threadIdx.x;
    const int tx = tid & 15, ty = tid >> 4;
    const int lr = tid >> 2, lc = (tid & 3) << 3;  // loader: row, 8-col chunk

    {   // stage Q tile once
        float4 a = *(const float4*)&Q[(q0 + lr) * HD + lc];
        float4 b = *(const float4*)&Q[(q0 + lr) * HD + lc + 4];
        *(float4*)&Qs[lr][lc] = a;
        *(float4*)&Qs[lr][lc + 4] = b;
    }
    if (tid < 64) { mrow[tid] = -INFINITY; lrow[tid] = 0.0f; }

    float o[8] = {0, 0, 0, 0, 0, 0, 0, 0};
    const int orow = tid >> 2;          // PV: this thread's q-row
    const int oc = (tid & 3) << 3;      // PV: 8-wide d chunk

    for (int kt = 0; kt < NTOK / 64; ++kt) {
        const int k0 = kt << 6;
        {   // stage K (transposed) and V
            float4 a = *(const float4*)&K[(k0 + lr) * HD + lc];
            float4 b = *(const float4*)&K[(k0 + lr) * HD + lc + 4];
            KsT[lc + 0][lr] = a.x; KsT[lc + 1][lr] = a.y;
            KsT[lc + 2][lr] = a.z; KsT[lc + 3][lr] = a.w;
            KsT[lc + 4][lr] = b.x; KsT[lc + 5][lr] = b.y;
            KsT[lc + 6][lr] = b.z; KsT[lc + 7][lr] = b.w;
            float4 va = *(const float4*)&V[(k0 + lr) * HD + lc];
            float4 vb = *(const float4*)&V[(k0 + lr) * HD + lc + 4];
            *(float4*)&Vs[lr][lc] = va;
            *(float4*)&Vs[lr][lc + 4] = vb;
        }
        __syncthreads();

        // ---- S = Q K^T (4x4 micro-tile per thread) ----
        float s[4][4] = {};
#pragma unroll
        for (int kk4 = 0; kk4 < 8; ++kk4) {
            float qa[4][4];
#pragma unroll
            for (int i = 0; i < 4; ++i) {
                float4 qv = *(const float4*)&Qs[ty * 4 + i][kk4 << 2];
                qa[i][0] = qv.x; qa[i][1] = qv.y; qa[i][2] = qv.z; qa[i][3] = qv.w;
            }
#pragma unroll
            for (int kk = 0; kk < 4; ++kk) {
                const float* kr = &KsT[(kk4 << 2) + kk][tx * 4];
                float b0 = kr[0], b1 = kr[1], b2 = kr[2], b3 = kr[3];
#pragma unroll
                for (int i = 0; i < 4; ++i) {
                    s[i][0] = fmaf(qa[i][kk], b0, s[i][0]);
                    s[i][1] = fmaf(qa[i][kk], b1, s[i][1]);
                    s[i][2] = fmaf(qa[i][kk], b2, s[i][2]);
                    s[i][3] = fmaf(qa[i][kk], b3, s[i][3]);
                }
            }
        }
        // mask + scale -> Ss
#pragma unroll
        for (int i = 0; i < 4; ++i) {
            const int4 av = *(const int4*)&adj[(q0 + ty * 4 + i) * NTOK + k0 + tx * 4];
            Ss[ty * 4 + i][tx * 4 + 0] = av.x ? s[i][0] * QSCALE : -INFINITY;
            Ss[ty * 4 + i][tx * 4 + 1] = av.y ? s[i][1] * QSCALE : -INFINITY;
            Ss[ty * 4 + i][tx * 4 + 2] = av.z ? s[i][2] * QSCALE : -INFINITY;
            Ss[ty * 4 + i][tx * 4 + 3] = av.w ? s[i][3] * QSCALE : -INFINITY;
        }
        __syncthreads();

        // ---- online softmax: partial row max (4 threads/row) ----
        {
            const int r = tid >> 2, c0 = (tid & 3) << 4;
            float mx = -INFINITY;
#pragma unroll
            for (int c = 0; c < 16; ++c) mx = fmaxf(mx, Ss[r][c0 + c]);
            red[r][tid & 3] = mx;
        }
        __syncthreads();
        if (tid < 64) {
            float tmax = fmaxf(fmaxf(red[tid][0], red[tid][1]),
                               fmaxf(red[tid][2], red[tid][3]));
            float mold = mrow[tid];
            float mnew = fmaxf(mold, tmax);
            float alpha;
            if (mnew == -INFINITY) alpha = 1.0f;      // fully-masked so far: no-op
            else alpha = __expf(mold - mnew);         // mold=-inf -> 0
            mrow[tid] = mnew; arow[tid] = alpha;
        }
        __syncthreads();
        // ---- exponentiate + partial row sum ----
        {
            const int r = tid >> 2, c0 = (tid & 3) << 4;
            const float mnew = mrow[r];
            float sum = 0.0f;
            if (mnew == -INFINITY) {
#pragma unroll
                for (int c = 0; c < 16; ++c) Ss[r][c0 + c] = 0.0f;
            } else {
#pragma unroll
                for (int c = 0; c < 16; ++c) {
                    float p = __expf(Ss[r][c0 + c] - mnew);
                    Ss[r][c0 + c] = p;
                    sum += p;
                }
            }
            red[r][tid & 3] = sum;
        }
        __syncthreads();
        if (tid < 64)
            lrow[tid] = lrow[tid] * arow[tid] +
                        red[tid][0] + red[tid][1] + red[tid][2] + red[tid][3];

        // ---- O = O*alpha + P V ----
        {
            const float alpha = arow[orow];
#pragma unroll
            for (int j = 0; j < 8; ++j) o[j] *= alpha;
#pragma unroll 8
            for (int k = 0; k < 64; ++k) {
                const float p = Ss[orow][k];
                float4 v0 = *(const float4*)&Vs[k][oc];
                float4 v1 = *(const float4*)&Vs[k][oc + 4];
                o[0] = fmaf(p, v0.x, o[0]); o[1] = fmaf(p, v0.y, o[1]);
                o[2] = fmaf(p, v0.z, o[2]); o[3] = fmaf(p, v0.w, o[3]);
                o[4] = fmaf(p, v1.x, o[4]); o[5] = fmaf(p, v1.y, o[5]);
                o[6] = fmaf(p, v1.z, o[6]); o[7] = fmaf(p, v1.w, o[7]);
            }
        }
        __syncthreads();   // protect Ks/Vs/Ss for next tile; lrow for next update
    }

    const float inv = 1.0f / lrow[orow];
    float4 r0, r1;
    r0.x = o[0] * inv; r0.y = o[1] * inv; r0.z = o[2] * inv; r0.w = o[3] * inv;
    r1.x = o[4] * inv; r1.y = o[5] * inv; r1.z = o[6] * inv; r1.w = o[7] * inv;
    float* dst = &attn_out[(q0 + orow) * EDIM + h * HD + oc];
    *(float4*)dst = r0;
    *(float4*)(dst + 4) = r1;
}

// ---------------- output projection: out = attn @ Wo^T + bo ----------------
__global__ __launch_bounds__(256) void out_gemm(
    const float* __restrict__ X, const float* __restrict__ W,
    const float* __restrict__ bias, float* __restrict__ Y)
{
    const int n0 = blockIdx.y << 6;
    const int m0 = blockIdx.x << 6;

    __shared__ float Xs[64][17];
    __shared__ float Wt[64][17];

    const int tid = threadIdx.x;
    const int tx = tid & 15, ty = tid >> 4;
    const int lr = tid >> 2, lc = (tid & 3) << 2;

    float acc[4][4] = {};
    for (int k0 = 0; k0 < 256; k0 += 16) {
        float4 xv = *(const float4*)&X[(m0 + lr) * 256 + k0 + lc];
        float4 wv = *(const float4*)&W[(n0 + lr) * 256 + k0 + lc];
        Xs[lr][lc + 0] = xv.x; Xs[lr][lc + 1] = xv.y;
        Xs[lr][lc + 2] = xv.z; Xs[lr][lc + 3] = xv.w;
        Wt[lr][lc + 0] = wv.x; Wt[lr][lc + 1] = wv.y;
        Wt[lr][lc + 2] = wv.z; Wt[lr][lc + 3] = wv.w;
        __syncthreads();
#pragma unroll
        for (int kk = 0; kk < 16; ++kk) {
            float a0 = Xs[ty * 4 + 0][kk], a1 = Xs[ty * 4 + 1][kk];
            float a2 = Xs[ty * 4 + 2][kk], a3 = Xs[ty * 4 + 3][kk];
            float b0 = Wt[tx * 4 + 0][kk], b1 = Wt[tx * 4 + 1][kk];
            float b2 = Wt[tx * 4 + 2][kk], b3 = Wt[tx * 4 + 3][kk];
            acc[0][0] = fmaf(a0, b0, acc[0][0]); acc[0][1] = fmaf(a0, b1, acc[0][1]);
            acc[0][2] = fmaf(a0, b2, acc[0][2]); acc[0][3] = fmaf(a0, b3, acc[0][3]);
            acc[1][0] = fmaf(a1, b0, acc[1][0]); acc[1][1] = fmaf(a1, b1, acc[1][1]);
            acc[1][2] = fmaf(a1, b2, acc[1][2]); acc[1][3] = fmaf(a1, b3, acc[1][3]);
            acc[2][0] = fmaf(a2, b0, acc[2][0]); acc[2][1] = fmaf(a2, b1, acc[2][1]);
            acc[2][2] = fmaf(a2, b2, acc[2][2]); acc[2][3] = fmaf(a2, b3, acc[2][3]);
            acc[3][0] = fmaf(a3, b0, acc[3][0]); acc[3][1] = fmaf(a3, b1, acc[3][1]);
            acc[3][2] = fmaf(a3, b2, acc[3][2]); acc[3][3] = fmaf(a3, b3, acc[3][3]);
        }
        __syncthreads();
    }
    const int e0 = n0 + tx * 4;
    const float b0 = bias[e0 + 0], b1 = bias[e0 + 1];
    const float b2 = bias[e0 + 2], b3 = bias[e0 + 3];
#pragma unroll
    for (int i = 0; i < 4; ++i) {
        const int row = m0 + ty * 4 + i;
        float4 r;
        r.x = acc[i][0] + b0; r.y = acc[i][1] + b1;
        r.z = acc[i][2] + b2; r.w = acc[i][3] + b3;
        *(float4*)&Y[row * EDIM + e0] = r;
    }
}

extern "C" void kernel_launch(void* const* d_in, const int* in_sizes, int n_in,
                              void* d_out, int out_size, void* d_ws, size_t ws_size,
                              hipStream_t stream) {
    (void)in_sizes; (void)n_in; (void)out_size; (void)ws_size;
    const float* x  = (const float*)d_in[0];
    const int*   adj = (const int*)d_in[1];
    const float* Wq = (const float*)d_in[2];
    const float* bq = (const float*)d_in[3];
    const float* Wk = (const float*)d_in[4];
    const float* bk = (const float*)d_in[5];
    const float* Wv = (const float*)d_in[6];
    const float* bv = (const float*)d_in[7];
    const float* Wo = (const float*)d_in[8];
    const float* bo = (const float*)d_in[9];

    float* ws = (float*)d_ws;
    float* q_ws = ws;                       // [H][N][32] = 1M floats
    float* k_ws = ws + (1 << 20);
    float* v_ws = ws + (2 << 20);
    float* a_ws = ws + (3 << 20);           // [N][256]

    qkv_gemm<<<dim3(64, 12), 256, 0, stream>>>(x, Wq, bq, Wk, bk, Wv, bv,
                                               q_ws, k_ws, v_ws);
    attn_kernel<<<dim3(64, 8), 256, 0, stream>>>(q_ws, k_ws, v_ws, adj, a_ws);
    out_gemm<<<dim3(64, 4), 256, 0, stream>>>(a_ws, Wo, bo, (float*)d_out);
}

// Round 2
// 329.884 us; speedup vs baseline: 2.3048x; 2.3048x over previous
//
#include <hip/hip_runtime.h>
#include <math.h>

// GraphAttentionBlock: B=1, N=4096, E=256, H=8, D=32, fp32 in/out.
// R2: bf16 MFMA flash attention. adjacency -> packed bitmask (ballot),
// qkv fp32-accum GEMM emits bf16 head-major, attn uses mfma_f32_16x16x32_bf16
// for QK^T and PV with register-resident online softmax.

#define NTOK 4096
#define EDIM 256
#define HEADS 8
#define HD 32
#define QSCALE 0.17677669529663687f  // 1/sqrt(32)
#define INF (__builtin_inff())

typedef __attribute__((ext_vector_type(8))) short bf16x8;
typedef __attribute__((ext_vector_type(4))) float f32x4;

static __device__ inline short f2bf(float f) {
    unsigned u = __float_as_uint(f);
    u = (u + 0x7FFFu + ((u >> 16) & 1u)) >> 16;   // RNE
    return (short)u;
}

// ---------------- adjacency -> bitmask: mask[row*64+kt] bit c = adj[row][kt*64+c]
__global__ __launch_bounds__(256) void pack_mask(
    const int* __restrict__ adj, unsigned long long* __restrict__ mask)
{
    const int gid = blockIdx.x * 256 + threadIdx.x;
    const unsigned long long m = __ballot(adj[gid] != 0);
    if ((threadIdx.x & 63) == 0) mask[gid >> 6] = m;
}

// ---------------- QKV projection: fp32 accum, bf16 head-major out ----------
__global__ __launch_bounds__(256) void qkv_gemm(
    const float* __restrict__ x,
    const float* __restrict__ Wq, const float* __restrict__ bq,
    const float* __restrict__ Wk, const float* __restrict__ bk,
    const float* __restrict__ Wv, const float* __restrict__ bv,
    short* __restrict__ qo, short* __restrict__ ko, short* __restrict__ vo)
{
    const int wsel = blockIdx.y >> 2;           // 0=Q 1=K 2=V
    const int n0 = (blockIdx.y & 3) << 6;
    const int m0 = blockIdx.x << 6;
    const float* __restrict__ W    = (wsel == 0) ? Wq : (wsel == 1) ? Wk : Wv;
    const float* __restrict__ bias = (wsel == 0) ? bq : (wsel == 1) ? bk : bv;
    short* __restrict__ out        = (wsel == 0) ? qo : (wsel == 1) ? ko : vo;

    __shared__ float Xs[64][17];
    __shared__ float Wt[64][17];

    const int tid = threadIdx.x;
    const int tx = tid & 15, ty = tid >> 4;
    const int lr = tid >> 2, lc = (tid & 3) << 2;

    float acc[4][4] = {};
    for (int k0 = 0; k0 < 256; k0 += 16) {
        float4 xv = *(const float4*)&x[(m0 + lr) * 256 + k0 + lc];
        float4 wv = *(const float4*)&W[(n0 + lr) * 256 + k0 + lc];
        Xs[lr][lc + 0] = xv.x; Xs[lr][lc + 1] = xv.y;
        Xs[lr][lc + 2] = xv.z; Xs[lr][lc + 3] = xv.w;
        Wt[lr][lc + 0] = wv.x; Wt[lr][lc + 1] = wv.y;
        Wt[lr][lc + 2] = wv.z; Wt[lr][lc + 3] = wv.w;
        __syncthreads();
#pragma unroll
        for (int kk = 0; kk < 16; ++kk) {
            float a0 = Xs[ty * 4 + 0][kk], a1 = Xs[ty * 4 + 1][kk];
            float a2 = Xs[ty * 4 + 2][kk], a3 = Xs[ty * 4 + 3][kk];
            float b0 = Wt[tx * 4 + 0][kk], b1 = Wt[tx * 4 + 1][kk];
            float b2 = Wt[tx * 4 + 2][kk], b3 = Wt[tx * 4 + 3][kk];
            acc[0][0] = fmaf(a0, b0, acc[0][0]); acc[0][1] = fmaf(a0, b1, acc[0][1]);
            acc[0][2] = fmaf(a0, b2, acc[0][2]); acc[0][3] = fmaf(a0, b3, acc[0][3]);
            acc[1][0] = fmaf(a1, b0, acc[1][0]); acc[1][1] = fmaf(a1, b1, acc[1][1]);
            acc[1][2] = fmaf(a1, b2, acc[1][2]); acc[1][3] = fmaf(a1, b3, acc[1][3]);
            acc[2][0] = fmaf(a2, b0, acc[2][0]); acc[2][1] = fmaf(a2, b1, acc[2][1]);
            acc[2][2] = fmaf(a2, b2, acc[2][2]); acc[2][3] = fmaf(a2, b3, acc[2][3]);
            acc[3][0] = fmaf(a3, b0, acc[3][0]); acc[3][1] = fmaf(a3, b1, acc[3][1]);
            acc[3][2] = fmaf(a3, b2, acc[3][2]); acc[3][3] = fmaf(a3, b3, acc[3][3]);
        }
        __syncthreads();
    }
    const int e0 = n0 + tx * 4;
    const float b0 = bias[e0 + 0], b1 = bias[e0 + 1];
    const float b2 = bias[e0 + 2], b3 = bias[e0 + 3];
    const int h = e0 >> 5, d0 = e0 & 31;
    const float sc = (wsel == 0) ? QSCALE : 1.0f;   // fold 1/sqrt(D) into Q
#pragma unroll
    for (int i = 0; i < 4; ++i) {
        const int row = m0 + ty * 4 + i;
        float rx = (acc[i][0] + b0) * sc, ry = (acc[i][1] + b1) * sc;
        float rz = (acc[i][2] + b2) * sc, rw = (acc[i][3] + b3) * sc;
        unsigned lo = (unsigned short)f2bf(rx) | ((unsigned)(unsigned short)f2bf(ry) << 16);
        unsigned hi = (unsigned short)f2bf(rz) | ((unsigned)(unsigned short)f2bf(rw) << 16);
        uint2 t; t.x = lo; t.y = hi;
        *(uint2*)&out[h * (NTOK * HD) + row * HD + d0] = t;
    }
}

// ---------------- MFMA flash attention with bitmask ------------------------
__global__ __launch_bounds__(256) void attn_mfma(
    const short* __restrict__ qg, const short* __restrict__ kg,
    const short* __restrict__ vg, const unsigned long long* __restrict__ maskp,
    float* __restrict__ attn_out)
{
    const int h = blockIdx.y;
    const int q0 = blockIdx.x << 6;
    const short* __restrict__ Q = qg + h * (NTOK * HD);
    const short* __restrict__ K = kg + h * (NTOK * HD);
    const short* __restrict__ V = vg + h * (NTOK * HD);

    __shared__ short Q_lds[64][40];   // stride 80B: b128-aligned, 2-way max
    __shared__ short K_lds[64][40];
    __shared__ short V_lds[64][40];
    __shared__ short P_lds[64][72];   // stride 144B: b128-aligned, 2-way max

    const int tid = threadIdx.x;
    const int wv = tid >> 6;          // wave 0..3 -> q-rows wv*16..wv*16+15
    const int lane = tid & 63;
    const int grp = lane >> 4;        // 16-lane group 0..3
    const int lcol = lane & 15;

    const int lr = tid >> 2, lc = (tid & 3) << 3;   // staging row / col8

    *(int4*)&Q_lds[lr][lc] = *(const int4*)&Q[(q0 + lr) * HD + lc];
    __syncthreads();
    // A-frag of Q (loop-invariant): A[m=lcol][k=grp*8+j]
    const bf16x8 qfrag = *(const bf16x8*)&Q_lds[wv * 16 + lcol][grp * 8];

    float m_i[4], l_i[4];
    f32x4 o[2] = {};                  // O C-layout: row=grp*4+j, col=c*16+lcol
#pragma unroll
    for (int j = 0; j < 4; ++j) { m_i[j] = -INF; l_i[j] = 0.f; }

    const int qrow_base = q0 + wv * 16 + grp * 4;

    for (int kt = 0; kt < 64; ++kt) {
        const int k0 = kt << 6;
        *(int4*)&K_lds[lr][lc] = *(const int4*)&K[(k0 + lr) * HD + lc];
        *(int4*)&V_lds[lr][lc] = *(const int4*)&V[(k0 + lr) * HD + lc];
        __syncthreads();

        // mask bits for this tile: row j, 64 key cols in one uint64 (broadcast)
        unsigned long long m64[4];
#pragma unroll
        for (int j = 0; j < 4; ++j)
            m64[j] = maskp[(qrow_base + j) * 64 + kt];

        // S = Q K^T : 4 MFMA (col blocks of 16 keys), K=32 = full head dim
        f32x4 s[4];
#pragma unroll
        for (int b = 0; b < 4; ++b) {
            const bf16x8 kf = *(const bf16x8*)&K_lds[b * 16 + lcol][grp * 8];
            s[b] = __builtin_amdgcn_mfma_f32_16x16x32_bf16(
                qfrag, kf, (f32x4){0.f, 0.f, 0.f, 0.f}, 0, 0, 0);
        }

        // online softmax per row j (rows of this 16-lane group)
        float alpha[4];
#pragma unroll
        for (int j = 0; j < 4; ++j) {
            float t0 = ((m64[j] >> lcol) & 1)        ? s[0][j] : -INF;
            float t1 = ((m64[j] >> (16 + lcol)) & 1) ? s[1][j] : -INF;
            float t2 = ((m64[j] >> (32 + lcol)) & 1) ? s[2][j] : -INF;
            float t3 = ((m64[j] >> (48 + lcol)) & 1) ? s[3][j] : -INF;
            float mx = fmaxf(fmaxf(t0, t1), fmaxf(t2, t3));
            mx = fmaxf(mx, __shfl_xor(mx, 1));
            mx = fmaxf(mx, __shfl_xor(mx, 2));
            mx = fmaxf(mx, __shfl_xor(mx, 4));
            mx = fmaxf(mx, __shfl_xor(mx, 8));
            const float mn = fmaxf(m_i[j], mx);
            const float al = (mn == -INF) ? 1.f : __expf(m_i[j] - mn);
            const int dead = (mn == -INF);
            float p0 = dead ? 0.f : __expf(t0 - mn);  // t=-inf -> exp -> 0
            float p1 = dead ? 0.f : __expf(t1 - mn);
            float p2 = dead ? 0.f : __expf(t2 - mn);
            float p3 = dead ? 0.f : __expf(t3 - mn);
            float rs = p0 + p1 + p2 + p3;
            rs += __shfl_xor(rs, 1);
            rs += __shfl_xor(rs, 2);
            rs += __shfl_xor(rs, 4);
            rs += __shfl_xor(rs, 8);
            m_i[j] = mn;
            alpha[j] = al;
            l_i[j] = l_i[j] * al + rs;
            // P: C-layout -> LDS (wave-private rows; lgkmcnt handles w->r)
            const int prow = wv * 16 + grp * 4 + j;
            P_lds[prow][lcol]      = f2bf(p0);
            P_lds[prow][16 + lcol] = f2bf(p1);
            P_lds[prow][32 + lcol] = f2bf(p2);
            P_lds[prow][48 + lcol] = f2bf(p3);
        }

        // O = O*alpha + P V : 4 MFMA (2 d-blocks x 2 key-halves)
#pragma unroll
        for (int c = 0; c < 2; ++c)
#pragma unroll
            for (int j = 0; j < 4; ++j) o[c][j] *= alpha[j];

        const bf16x8 pf0 = *(const bf16x8*)&P_lds[wv * 16 + lcol][grp * 8];
        const bf16x8 pf1 = *(const bf16x8*)&P_lds[wv * 16 + lcol][32 + grp * 8];
#pragma unroll
        for (int c = 0; c < 2; ++c) {
            bf16x8 vf0, vf1;
#pragma unroll
            for (int j = 0; j < 8; ++j) {
                vf0[j] = V_lds[grp * 8 + j][c * 16 + lcol];
                vf1[j] = V_lds[32 + grp * 8 + j][c * 16 + lcol];
            }
            o[c] = __builtin_amdgcn_mfma_f32_16x16x32_bf16(pf0, vf0, o[c], 0, 0, 0);
            o[c] = __builtin_amdgcn_mfma_f32_16x16x32_bf16(pf1, vf1, o[c], 0, 0, 0);
        }
        __syncthreads();   // all waves done with K/V before restaging
    }

    float inv[4];
#pragma unroll
    for (int j = 0; j < 4; ++j) inv[j] = 1.f / l_i[j];
#pragma unroll
    for (int c = 0; c < 2; ++c)
#pragma unroll
        for (int j = 0; j < 4; ++j)
            attn_out[(qrow_base + j) * EDIM + h * HD + c * 16 + lcol] = o[c][j] * inv[j];
}

// ---------------- output projection: out = attn @ Wo^T + bo ----------------
__global__ __launch_bounds__(256) void out_gemm(
    const float* __restrict__ X, const float* __restrict__ W,
    const float* __restrict__ bias, float* __restrict__ Y)
{
    const int n0 = blockIdx.y << 6;
    const int m0 = blockIdx.x << 6;

    __shared__ float Xs[64][17];
    __shared__ float Wt[64][17];

    const int tid = threadIdx.x;
    const int tx = tid & 15, ty = tid >> 4;
    const int lr = tid >> 2, lc = (tid & 3) << 2;

    float acc[4][4] = {};
    for (int k0 = 0; k0 < 256; k0 += 16) {
        float4 xv = *(const float4*)&X[(m0 + lr) * 256 + k0 + lc];
        float4 wv = *(const float4*)&W[(n0 + lr) * 256 + k0 + lc];
        Xs[lr][lc + 0] = xv.x; Xs[lr][lc + 1] = xv.y;
        Xs[lr][lc + 2] = xv.z; Xs[lr][lc + 3] = xv.w;
        Wt[lr][lc + 0] = wv.x; Wt[lr][lc + 1] = wv.y;
        Wt[lr][lc + 2] = wv.z; Wt[lr][lc + 3] = wv.w;
        __syncthreads();
#pragma unroll
        for (int kk = 0; kk < 16; ++kk) {
            float a0 = Xs[ty * 4 + 0][kk], a1 = Xs[ty * 4 + 1][kk];
            float a2 = Xs[ty * 4 + 2][kk], a3 = Xs[ty * 4 + 3][kk];
            float b0 = Wt[tx * 4 + 0][kk], b1 = Wt[tx * 4 + 1][kk];
            float b2 = Wt[tx * 4 + 2][kk], b3 = Wt[tx * 4 + 3][kk];
            acc[0][0] = fmaf(a0, b0, acc[0][0]); acc[0][1] = fmaf(a0, b1, acc[0][1]);
            acc[0][2] = fmaf(a0, b2, acc[0][2]); acc[0][3] = fmaf(a0, b3, acc[0][3]);
            acc[1][0] = fmaf(a1, b0, acc[1][0]); acc[1][1] = fmaf(a1, b1, acc[1][1]);
            acc[1][2] = fmaf(a1, b2, acc[1][2]); acc[1][3] = fmaf(a1, b3, acc[1][3]);
            acc[2][0] = fmaf(a2, b0, acc[2][0]); acc[2][1] = fmaf(a2, b1, acc[2][1]);
            acc[2][2] = fmaf(a2, b2, acc[2][2]); acc[2][3] = fmaf(a2, b3, acc[2][3]);
            acc[3][0] = fmaf(a3, b0, acc[3][0]); acc[3][1] = fmaf(a3, b1, acc[3][1]);
            acc[3][2] = fmaf(a3, b2, acc[3][2]); acc[3][3] = fmaf(a3, b3, acc[3][3]);
        }
        __syncthreads();
    }
    const int e0 = n0 + tx * 4;
    const float b0 = bias[e0 + 0], b1 = bias[e0 + 1];
    const float b2 = bias[e0 + 2], b3 = bias[e0 + 3];
#pragma unroll
    for (int i = 0; i < 4; ++i) {
        const int row = m0 + ty * 4 + i;
        float4 r;
        r.x = acc[i][0] + b0; r.y = acc[i][1] + b1;
        r.z = acc[i][2] + b2; r.w = acc[i][3] + b3;
        *(float4*)&Y[row * EDIM + e0] = r;
    }
}

extern "C" void kernel_launch(void* const* d_in, const int* in_sizes, int n_in,
                              void* d_out, int out_size, void* d_ws, size_t ws_size,
                              hipStream_t stream) {
    (void)in_sizes; (void)n_in; (void)out_size; (void)ws_size;
    const float* x  = (const float*)d_in[0];
    const int*  adj = (const int*)d_in[1];
    const float* Wq = (const float*)d_in[2];
    const float* bq = (const float*)d_in[3];
    const float* Wk = (const float*)d_in[4];
    const float* bk = (const float*)d_in[5];
    const float* Wv = (const float*)d_in[6];
    const float* bv = (const float*)d_in[7];
    const float* Wo = (const float*)d_in[8];
    const float* bo = (const float*)d_in[9];

    char* ws = (char*)d_ws;
    short* q_ws = (short*)(ws);                         // 2 MB bf16 [H][N][32]
    short* k_ws = (short*)(ws + (2u << 20));            // 2 MB
    short* v_ws = (short*)(ws + (4u << 20));            // 2 MB
    float* a_ws = (float*)(ws + (6u << 20));            // 4 MB fp32 [N][256]
    unsigned long long* mask_ws =
        (unsigned long long*)(ws + (10u << 20));        // 2 MB bitmask

    pack_mask<<<dim3((NTOK * NTOK) / 256), 256, 0, stream>>>(adj, mask_ws);
    qkv_gemm<<<dim3(64, 12), 256, 0, stream>>>(x, Wq, bq, Wk, bk, Wv, bv,
                                               q_ws, k_ws, v_ws);
    attn_mfma<<<dim3(64, 8), 256, 0, stream>>>(q_ws, k_ws, v_ws, mask_ws, a_ws);
    out_gemm<<<dim3(64, 4), 256, 0, stream>>>(a_ws, Wo, bo, (float*)d_out);
}

// Round 3
// 298.258 us; speedup vs baseline: 2.5492x; 1.1060x over previous
//
#include <hip/hip_runtime.h>
#include <math.h>

// GraphAttentionBlock: B=1, N=4096, E=256, H=8, D=32, fp32 in/out.
// R3: barrier-free MFMA flash attention. No-max softmax (exp(s-8) via MFMA
// C-init), Q/K/V^T fragments loaded directly from global (L2-resident),
// LDS only for P C->A layout transform (wave-private). Split-K x4 with
// additive (o,l) partials combined in out_gemm staging.

#define NTOK 4096
#define EDIM 256
#define HEADS 8
#define HD 32
#define NSPLIT 4
#define QSCALE 0.17677669529663687f  // 1/sqrt(32)
#define INF (__builtin_inff())

typedef __attribute__((ext_vector_type(8))) short bf16x8;
typedef __attribute__((ext_vector_type(4))) float f32x4;

static __device__ inline short f2bf(float f) {
    unsigned u = __float_as_uint(f);
    u = (u + 0x7FFFu + ((u >> 16) & 1u)) >> 16;   // RNE
    return (short)u;
}

// ---------------- adjacency -> bitmask: mask[row*64+kt] bit c = adj[row][kt*64+c]
__global__ __launch_bounds__(256) void pack_mask(
    const int* __restrict__ adj, unsigned long long* __restrict__ mask)
{
    const int gid = blockIdx.x * 256 + threadIdx.x;
    const unsigned long long m = __ballot(adj[gid] != 0);
    if ((threadIdx.x & 63) == 0) mask[gid >> 6] = m;
}

// ---------------- QKV projection: fp32 accum, bf16 out; V written transposed
__global__ __launch_bounds__(256) void qkv_gemm(
    const float* __restrict__ x,
    const float* __restrict__ Wq, const float* __restrict__ bq,
    const float* __restrict__ Wk, const float* __restrict__ bk,
    const float* __restrict__ Wv, const float* __restrict__ bv,
    short* __restrict__ qo, short* __restrict__ ko, short* __restrict__ vto)
{
    const int wsel = blockIdx.y >> 2;           // 0=Q 1=K 2=V
    const int n0 = (blockIdx.y & 3) << 6;
    const int m0 = blockIdx.x << 6;
    const float* __restrict__ W    = (wsel == 0) ? Wq : (wsel == 1) ? Wk : Wv;
    const float* __restrict__ bias = (wsel == 0) ? bq : (wsel == 1) ? bk : bv;

    __shared__ float Xs[64][17];
    __shared__ float Wt[64][17];

    const int tid = threadIdx.x;
    const int tx = tid & 15, ty = tid >> 4;
    const int lr = tid >> 2, lc = (tid & 3) << 2;

    float acc[4][4] = {};
    for (int k0 = 0; k0 < 256; k0 += 16) {
        float4 xv = *(const float4*)&x[(m0 + lr) * 256 + k0 + lc];
        float4 wv = *(const float4*)&W[(n0 + lr) * 256 + k0 + lc];
        Xs[lr][lc + 0] = xv.x; Xs[lr][lc + 1] = xv.y;
        Xs[lr][lc + 2] = xv.z; Xs[lr][lc + 3] = xv.w;
        Wt[lr][lc + 0] = wv.x; Wt[lr][lc + 1] = wv.y;
        Wt[lr][lc + 2] = wv.z; Wt[lr][lc + 3] = wv.w;
        __syncthreads();
#pragma unroll
        for (int kk = 0; kk < 16; ++kk) {
            float a0 = Xs[ty * 4 + 0][kk], a1 = Xs[ty * 4 + 1][kk];
            float a2 = Xs[ty * 4 + 2][kk], a3 = Xs[ty * 4 + 3][kk];
            float b0 = Wt[tx * 4 + 0][kk], b1 = Wt[tx * 4 + 1][kk];
            float b2 = Wt[tx * 4 + 2][kk], b3 = Wt[tx * 4 + 3][kk];
            acc[0][0] = fmaf(a0, b0, acc[0][0]); acc[0][1] = fmaf(a0, b1, acc[0][1]);
            acc[0][2] = fmaf(a0, b2, acc[0][2]); acc[0][3] = fmaf(a0, b3, acc[0][3]);
            acc[1][0] = fmaf(a1, b0, acc[1][0]); acc[1][1] = fmaf(a1, b1, acc[1][1]);
            acc[1][2] = fmaf(a1, b2, acc[1][2]); acc[1][3] = fmaf(a1, b3, acc[1][3]);
            acc[2][0] = fmaf(a2, b0, acc[2][0]); acc[2][1] = fmaf(a2, b1, acc[2][1]);
            acc[2][2] = fmaf(a2, b2, acc[2][2]); acc[2][3] = fmaf(a2, b3, acc[2][3]);
            acc[3][0] = fmaf(a3, b0, acc[3][0]); acc[3][1] = fmaf(a3, b1, acc[3][1]);
            acc[3][2] = fmaf(a3, b2, acc[3][2]); acc[3][3] = fmaf(a3, b3, acc[3][3]);
        }
        __syncthreads();
    }
    const int e0 = n0 + tx * 4;
    const float bl[4] = {bias[e0 + 0], bias[e0 + 1], bias[e0 + 2], bias[e0 + 3]};
    const int h = e0 >> 5, d0 = e0 & 31;

    if (wsel == 2) {
        // V transposed: vt[h][d][n]
#pragma unroll
        for (int l = 0; l < 4; ++l) {
            short s0 = f2bf(acc[0][l] + bl[l]);
            short s1 = f2bf(acc[1][l] + bl[l]);
            short s2 = f2bf(acc[2][l] + bl[l]);
            short s3 = f2bf(acc[3][l] + bl[l]);
            uint2 t;
            t.x = (unsigned short)s0 | ((unsigned)(unsigned short)s1 << 16);
            t.y = (unsigned short)s2 | ((unsigned)(unsigned short)s3 << 16);
            *(uint2*)&vto[h * (HD * NTOK) + (d0 + l) * NTOK + (m0 + ty * 4)] = t;
        }
    } else {
        short* __restrict__ out = (wsel == 0) ? qo : ko;
        const float sc = (wsel == 0) ? QSCALE : 1.0f;   // fold 1/sqrt(D) into Q
#pragma unroll
        for (int i = 0; i < 4; ++i) {
            const int row = m0 + ty * 4 + i;
            float rx = (acc[i][0] + bl[0]) * sc, ry = (acc[i][1] + bl[1]) * sc;
            float rz = (acc[i][2] + bl[2]) * sc, rw = (acc[i][3] + bl[3]) * sc;
            uint2 t;
            t.x = (unsigned short)f2bf(rx) | ((unsigned)(unsigned short)f2bf(ry) << 16);
            t.y = (unsigned short)f2bf(rz) | ((unsigned)(unsigned short)f2bf(rw) << 16);
            *(uint2*)&out[h * (NTOK * HD) + row * HD + d0] = t;
        }
    }
}

// ---------------- barrier-free MFMA flash attention ------------------------
__global__ __launch_bounds__(256) void attn_mfma(
    const short* __restrict__ qg, const short* __restrict__ kg,
    const short* __restrict__ vtg, const unsigned long long* __restrict__ maskp,
    float* __restrict__ o_part, float* __restrict__ l_part)
{
    const int h = blockIdx.y;
    const int split = blockIdx.z;
    const int q0 = blockIdx.x << 6;
    const short* __restrict__ Q  = qg  + h * (NTOK * HD);
    const short* __restrict__ K  = kg  + h * (NTOK * HD);
    const short* __restrict__ Vt = vtg + h * (HD * NTOK);

    __shared__ short P_lds[64][72];   // 144B stride: b128-aligned rows

    const int tid = threadIdx.x;
    const int wv = tid >> 6;          // wave -> q rows wv*16..+15
    const int lane = tid & 63;
    const int grp = lane >> 4;
    const int lcol = lane & 15;
    const int qrow = q0 + wv * 16;
    const int qrow_base = qrow + grp * 4;   // this group's 4 C-layout rows

    // Q A-fragment direct from global: A[m=lcol][k=grp*8+j]
    const bf16x8 qfrag = *(const bf16x8*)&Q[(qrow + lcol) * HD + grp * 8];

    f32x4 o[2] = {};                  // O C-layout: row=grp*4+j, col=c*16+lcol
    float lpart[4] = {0.f, 0.f, 0.f, 0.f};

    const int kt_begin = split * (64 / NSPLIT);
    const int kt_end = kt_begin + (64 / NSPLIT);
    for (int kt = kt_begin; kt < kt_end; ++kt) {
        const int k0 = kt << 6;

        // K B-fragments + mask, direct from global (L2-resident)
        bf16x8 kf[4];
#pragma unroll
        for (int b = 0; b < 4; ++b)
            kf[b] = *(const bf16x8*)&K[(k0 + b * 16 + lcol) * HD + grp * 8];
        unsigned long long m64[4];
#pragma unroll
        for (int j = 0; j < 4; ++j)
            m64[j] = maskp[(qrow_base + j) * 64 + kt];

        // S = Q K^T - 8  (C-init = -8 folds the exp-shift for free)
        f32x4 s[4];
#pragma unroll
        for (int b = 0; b < 4; ++b)
            s[b] = __builtin_amdgcn_mfma_f32_16x16x32_bf16(
                qfrag, kf[b], (f32x4){-8.f, -8.f, -8.f, -8.f}, 0, 0, 0);

        // no-max softmax: p = exp(s-8) (masked -> exp(-inf) = 0)
#pragma unroll
        for (int j = 0; j < 4; ++j) {
            float p0 = __expf(((m64[j] >> lcol) & 1)        ? s[0][j] : -INF);
            float p1 = __expf(((m64[j] >> (16 + lcol)) & 1) ? s[1][j] : -INF);
            float p2 = __expf(((m64[j] >> (32 + lcol)) & 1) ? s[2][j] : -INF);
            float p3 = __expf(((m64[j] >> (48 + lcol)) & 1) ? s[3][j] : -INF);
            lpart[j] += (p0 + p1) + (p2 + p3);
            const int prow = wv * 16 + grp * 4 + j;    // wave-private rows
            P_lds[prow][lcol]      = f2bf(p0);
            P_lds[prow][16 + lcol] = f2bf(p1);
            P_lds[prow][32 + lcol] = f2bf(p2);
            P_lds[prow][48 + lcol] = f2bf(p3);
        }

        // P A-frags (C->A transform via LDS; lgkmcnt orders within wave)
        const bf16x8 pf0 = *(const bf16x8*)&P_lds[wv * 16 + lcol][grp * 8];
        const bf16x8 pf1 = *(const bf16x8*)&P_lds[wv * 16 + lcol][32 + grp * 8];
        // V^T B-frags direct from global: B[k=grp*8+j][n=lcol]
#pragma unroll
        for (int c = 0; c < 2; ++c) {
            const bf16x8 vf0 = *(const bf16x8*)&Vt[(c * 16 + lcol) * NTOK + k0 + grp * 8];
            const bf16x8 vf1 = *(const bf16x8*)&Vt[(c * 16 + lcol) * NTOK + k0 + 32 + grp * 8];
            o[c] = __builtin_amdgcn_mfma_f32_16x16x32_bf16(pf0, vf0, o[c], 0, 0, 0);
            o[c] = __builtin_amdgcn_mfma_f32_16x16x32_bf16(pf1, vf1, o[c], 0, 0, 0);
        }
    }

    // deferred l reduction: sum across the 16 lanes of each group (once)
#pragma unroll
    for (int j = 0; j < 4; ++j) {
        float v = lpart[j];
        v += __shfl_xor(v, 1); v += __shfl_xor(v, 2);
        v += __shfl_xor(v, 4); v += __shfl_xor(v, 8);
        lpart[j] = v;
    }

    float* __restrict__ ob = o_part + split * (NTOK * EDIM);
#pragma unroll
    for (int c = 0; c < 2; ++c)
#pragma unroll
        for (int j = 0; j < 4; ++j)
            ob[(qrow_base + j) * EDIM + h * HD + c * 16 + lcol] = o[c][j];
    if (lcol == 0) {
#pragma unroll
        for (int j = 0; j < 4; ++j)
            l_part[split * (NTOK * HEADS) + (qrow_base + j) * HEADS + h] = lpart[j];
    }
}

// -------- output projection with split-K combine: out = ((Σo)/(Σl)) @ Wo^T + bo
__global__ __launch_bounds__(256) void out_gemm(
    const float* __restrict__ o_part, const float* __restrict__ l_part,
    const float* __restrict__ W, const float* __restrict__ bias,
    float* __restrict__ Y)
{
    const int n0 = blockIdx.y << 6;
    const int m0 = blockIdx.x << 6;

    __shared__ float Xs[64][17];
    __shared__ float Wt[64][17];

    const int tid = threadIdx.x;
    const int tx = tid & 15, ty = tid >> 4;
    const int lr = tid >> 2, lc = (tid & 3) << 2;

    float acc[4][4] = {};
    for (int k0 = 0; k0 < 256; k0 += 16) {
        const int row = m0 + lr, col = k0 + lc;
        float4 a0 = *(const float4*)&o_part[0 * (NTOK * EDIM) + row * EDIM + col];
        float4 a1 = *(const float4*)&o_part[1 * (NTOK * EDIM) + row * EDIM + col];
        float4 a2 = *(const float4*)&o_part[2 * (NTOK * EDIM) + row * EDIM + col];
        float4 a3 = *(const float4*)&o_part[3 * (NTOK * EDIM) + row * EDIM + col];
        const int hh = col >> 5;
        float ls = l_part[0 * (NTOK * HEADS) + row * HEADS + hh]
                 + l_part[1 * (NTOK * HEADS) + row * HEADS + hh]
                 + l_part[2 * (NTOK * HEADS) + row * HEADS + hh]
                 + l_part[3 * (NTOK * HEADS) + row * HEADS + hh];
        const float inv = 1.0f / ls;
        float4 wv = *(const float4*)&W[(n0 + lr) * 256 + col];
        Xs[lr][lc + 0] = (a0.x + a1.x + a2.x + a3.x) * inv;
        Xs[lr][lc + 1] = (a0.y + a1.y + a2.y + a3.y) * inv;
        Xs[lr][lc + 2] = (a0.z + a1.z + a2.z + a3.z) * inv;
        Xs[lr][lc + 3] = (a0.w + a1.w + a2.w + a3.w) * inv;
        Wt[lr][lc + 0] = wv.x; Wt[lr][lc + 1] = wv.y;
        Wt[lr][lc + 2] = wv.z; Wt[lr][lc + 3] = wv.w;
        __syncthreads();
#pragma unroll
        for (int kk = 0; kk < 16; ++kk) {
            float a0f = Xs[ty * 4 + 0][kk], a1f = Xs[ty * 4 + 1][kk];
            float a2f = Xs[ty * 4 + 2][kk], a3f = Xs[ty * 4 + 3][kk];
            float b0 = Wt[tx * 4 + 0][kk], b1 = Wt[tx * 4 + 1][kk];
            float b2 = Wt[tx * 4 + 2][kk], b3 = Wt[tx * 4 + 3][kk];
            acc[0][0] = fmaf(a0f, b0, acc[0][0]); acc[0][1] = fmaf(a0f, b1, acc[0][1]);
            acc[0][2] = fmaf(a0f, b2, acc[0][2]); acc[0][3] = fmaf(a0f, b3, acc[0][3]);
            acc[1][0] = fmaf(a1f, b0, acc[1][0]); acc[1][1] = fmaf(a1f, b1, acc[1][1]);
            acc[1][2] = fmaf(a1f, b2, acc[1][2]); acc[1][3] = fmaf(a1f, b3, acc[1][3]);
            acc[2][0] = fmaf(a2f, b0, acc[2][0]); acc[2][1] = fmaf(a2f, b1, acc[2][1]);
            acc[2][2] = fmaf(a2f, b2, acc[2][2]); acc[2][3] = fmaf(a2f, b3, acc[2][3]);
            acc[3][0] = fmaf(a3f, b0, acc[3][0]); acc[3][1] = fmaf(a3f, b1, acc[3][1]);
            acc[3][2] = fmaf(a3f, b2, acc[3][2]); acc[3][3] = fmaf(a3f, b3, acc[3][3]);
        }
        __syncthreads();
    }
    const int e0 = n0 + tx * 4;
    const float b0 = bias[e0 + 0], b1 = bias[e0 + 1];
    const float b2 = bias[e0 + 2], b3 = bias[e0 + 3];
#pragma unroll
    for (int i = 0; i < 4; ++i) {
        const int row = m0 + ty * 4 + i;
        float4 r;
        r.x = acc[i][0] + b0; r.y = acc[i][1] + b1;
        r.z = acc[i][2] + b2; r.w = acc[i][3] + b3;
        *(float4*)&Y[row * EDIM + e0] = r;
    }
}

extern "C" void kernel_launch(void* const* d_in, const int* in_sizes, int n_in,
                              void* d_out, int out_size, void* d_ws, size_t ws_size,
                              hipStream_t stream) {
    (void)in_sizes; (void)n_in; (void)out_size; (void)ws_size;
    const float* x  = (const float*)d_in[0];
    const int*  adj = (const int*)d_in[1];
    const float* Wq = (const float*)d_in[2];
    const float* bq = (const float*)d_in[3];
    const float* Wk = (const float*)d_in[4];
    const float* bk = (const float*)d_in[5];
    const float* Wv = (const float*)d_in[6];
    const float* bv = (const float*)d_in[7];
    const float* Wo = (const float*)d_in[8];
    const float* bo = (const float*)d_in[9];

    char* ws = (char*)d_ws;
    short* q_ws  = (short*)(ws);                        // 2 MB bf16 [H][N][32]
    short* k_ws  = (short*)(ws + (2u << 20));           // 2 MB
    short* vt_ws = (short*)(ws + (4u << 20));           // 2 MB bf16 [H][32][N]
    unsigned long long* mask_ws =
        (unsigned long long*)(ws + (6u << 20));         // 2 MB bitmask
    float* o_part = (float*)(ws + (8u << 20));          // 16 MB fp32 [4][N][256]
    float* l_part = (float*)(ws + (24u << 20));         // 512 KB fp32 [4][N][8]

    pack_mask<<<dim3((NTOK * NTOK) / 256), 256, 0, stream>>>(adj, mask_ws);
    qkv_gemm<<<dim3(64, 12), 256, 0, stream>>>(x, Wq, bq, Wk, bk, Wv, bv,
                                               q_ws, k_ws, vt_ws);
    attn_mfma<<<dim3(64, HEADS, NSPLIT), 256, 0, stream>>>(
        q_ws, k_ws, vt_ws, mask_ws, o_part, l_part);
    out_gemm<<<dim3(64, 4), 256, 0, stream>>>(o_part, l_part, Wo, bo,
                                              (float*)d_out);
}

// Round 4
// 262.604 us; speedup vs baseline: 2.8953x; 1.1358x over previous
//
#include <hip/hip_runtime.h>
#include <math.h>

// GraphAttentionBlock: B=1, N=4096, E=256, H=8, D=32, fp32 in/out.
// R4: (1) attn: C-layout-permuted bitmask -> scalar s_load + single v_cndmask
// (sgpr-pair mask) per 64 elements; exp2 fold (log2e into Q scale, -8*log2e
// into MFMA C-init); cheap round-half-up f2bf for P; K-fragment register
// prefetch. (2) qkv & out projections moved to bf16 MFMA (x/W cast once);
// split-K combine + bf16 cast in a small kernel.

#define NTOK 4096
#define EDIM 256
#define HEADS 8
#define HD 32
#define NSPLIT 4
#define QSCALE 0.17677669529663687f            // 1/sqrt(32)
#define LOG2E 1.4426950408889634f
#define CINIT (-11.541560327111707f)           // -8 * log2(e)

typedef __attribute__((ext_vector_type(8))) short bf16x8;
typedef __attribute__((ext_vector_type(4))) float f32x4;
typedef __attribute__((ext_vector_type(4))) unsigned long long u64x4;

static __device__ inline short f2bf(float f) {          // RNE
    unsigned u = __float_as_uint(f);
    u = (u + 0x7FFFu + ((u >> 16) & 1u)) >> 16;
    return (short)u;
}
static __device__ inline unsigned f2bf_fast(float f) {  // round-half-up
    return (__float_as_uint(f) + 0x8000u) >> 16;
}
static __device__ inline float exp2_fast(float x) {
    float r;
    asm("v_exp_f32 %0, %1" : "=v"(r) : "v"(x));
    return r;
}
// p = (mask bit for this lane) ? v : 0   -- one VALU op, sgpr-pair mask
static __device__ inline float sel_mask(float v, unsigned long long m) {
    float r;
    asm("v_cndmask_b32 %0, 0, %1, %2" : "=v"(r) : "v"(v), "s"(m));
    return r;
}

// ---- adjacency -> C-layout-permuted bitmask ------------------------------
// maskC[qt*1024 + j*256 + kb]: bit l = adj[qt*16 + (l>>4)*4 + j][kb*16 + (l&15)]
__global__ __launch_bounds__(256) void pack_mask(
    const int* __restrict__ adj, unsigned long long* __restrict__ maskC)
{
    const int wid = blockIdx.x * 4 + (threadIdx.x >> 6);
    const int l = threadIdx.x & 63;
    const int qt = wid >> 10, j = (wid >> 8) & 3, kb = wid & 255;
    const int row = qt * 16 + (l >> 4) * 4 + j;
    const int col = kb * 16 + (l & 15);
    const unsigned long long m = __ballot(adj[row * NTOK + col] != 0);
    if (l == 0) maskC[wid] = m;
}

// ---- fp32 -> bf16 cast (RNE), 4 elements/thread --------------------------
__global__ __launch_bounds__(256) void cast_bf(
    const float* __restrict__ src, short* __restrict__ dst, int n4)
{
    const int gid = blockIdx.x * 256 + threadIdx.x;
    if (gid >= n4) return;
    float4 v = *(const float4*)&src[gid * 4];
    uint2 t;
    t.x = (unsigned short)f2bf(v.x) | ((unsigned)(unsigned short)f2bf(v.y) << 16);
    t.y = (unsigned short)f2bf(v.z) | ((unsigned)(unsigned short)f2bf(v.w) << 16);
    *(uint2*)&dst[gid * 4] = t;
}

// ---- QKV projection via MFMA: q/k head-major, v transposed ---------------
// grid (64, 48): y>>4 = wsel, (y&15)*16 = n0; 4 waves each own 16 tokens.
__global__ __launch_bounds__(256) void qkv_mfma(
    const short* __restrict__ xb,
    const short* __restrict__ Wqb, const short* __restrict__ Wkb,
    const short* __restrict__ Wvb,
    const float* __restrict__ bq, const float* __restrict__ bk,
    const float* __restrict__ bv,
    short* __restrict__ qo, short* __restrict__ ko, short* __restrict__ vto)
{
    const int tid = threadIdx.x;
    const int wv = tid >> 6, lane = tid & 63;
    const int grp = lane >> 4, lcol = lane & 15;
    const int wsel = blockIdx.y >> 4;
    const int n0 = (blockIdx.y & 15) << 4;
    const int m0 = blockIdx.x * 64 + wv * 16;
    const short* __restrict__ W = (wsel == 0) ? Wqb : (wsel == 1) ? Wkb : Wvb;
    const float* __restrict__ bias = (wsel == 0) ? bq : (wsel == 1) ? bk : bv;

    f32x4 acc = {};
#pragma unroll
    for (int k = 0; k < 8; ++k) {
        const bf16x8 a = *(const bf16x8*)&xb[(m0 + lcol) * 256 + k * 32 + grp * 8];
        const bf16x8 b = *(const bf16x8*)&W[(n0 + lcol) * 256 + k * 32 + grp * 8];
        acc = __builtin_amdgcn_mfma_f32_16x16x32_bf16(a, b, acc, 0, 0, 0);
    }
    const int feat = n0 + lcol;
    const float bval = bias[feat];
    const int h = feat >> 5, d = feat & 31;
    if (wsel == 2) {
        // vt[h][d][tok], 4 consecutive tokens packed -> one 8B store
        uint2 t;
        t.x = (unsigned short)f2bf(acc[0] + bval) |
              ((unsigned)(unsigned short)f2bf(acc[1] + bval) << 16);
        t.y = (unsigned short)f2bf(acc[2] + bval) |
              ((unsigned)(unsigned short)f2bf(acc[3] + bval) << 16);
        *(uint2*)&vto[h * (HD * NTOK) + d * NTOK + (m0 + grp * 4)] = t;
    } else {
        short* __restrict__ out = (wsel == 0) ? qo : ko;
        const float sc = (wsel == 0) ? (QSCALE * LOG2E) : 1.0f;
#pragma unroll
        for (int j = 0; j < 4; ++j)
            out[h * (NTOK * HD) + (m0 + grp * 4 + j) * HD + d] =
                f2bf((acc[j] + bval) * sc);
    }
}

// ---- barrier-free MFMA flash attention -----------------------------------
__global__ __launch_bounds__(256) void attn_mfma(
    const short* __restrict__ qg, const short* __restrict__ kg,
    const short* __restrict__ vtg, const unsigned long long* __restrict__ maskC,
    float* __restrict__ o_part, float* __restrict__ l_part)
{
    const int h = blockIdx.y;
    const int split = blockIdx.z;
    const int q0 = blockIdx.x << 6;
    const short* __restrict__ Q  = qg  + h * (NTOK * HD);
    const short* __restrict__ K  = kg  + h * (NTOK * HD);
    const short* __restrict__ Vt = vtg + h * (HD * NTOK);

    __shared__ short P_lds[64][72];   // 144B rows: b128-aligned

    const int tid = threadIdx.x;
    const int wv = tid >> 6;
    const int lane = tid & 63;
    const int grp = lane >> 4;
    const int lcol = lane & 15;
    const int qrow = q0 + wv * 16;
    const int qrow_base = qrow + grp * 4;

    const bf16x8 qfrag = *(const bf16x8*)&Q[(qrow + lcol) * HD + grp * 8];

    // wave-uniform mask row base (scalar loads)
    const int qt = __builtin_amdgcn_readfirstlane(blockIdx.x * 4 + wv);
    const unsigned long long* __restrict__ mbase = maskC + (size_t)qt * 1024;

    f32x4 o[2] = {};
    float lsum[4] = {0.f, 0.f, 0.f, 0.f};

    const int kt_begin = split * (64 / NSPLIT);
    const int kt_end = kt_begin + (64 / NSPLIT);

    bf16x8 kf[4];
#pragma unroll
    for (int b = 0; b < 4; ++b)
        kf[b] = *(const bf16x8*)&K[((kt_begin << 6) + b * 16 + lcol) * HD + grp * 8];

    for (int kt = kt_begin; kt < kt_end; ++kt) {
        const int k0 = kt << 6;
        // scalar mask words: w[j][b] for this 64-key tile
        const u64x4 w0 = *(const u64x4*)(mbase + 0 * 256 + 4 * kt);
        const u64x4 w1 = *(const u64x4*)(mbase + 1 * 256 + 4 * kt);
        const u64x4 w2 = *(const u64x4*)(mbase + 2 * 256 + 4 * kt);
        const u64x4 w3 = *(const u64x4*)(mbase + 3 * 256 + 4 * kt);

        // S' = (Q*scale*log2e) K^T - 8*log2e
        f32x4 s[4];
#pragma unroll
        for (int b = 0; b < 4; ++b)
            s[b] = __builtin_amdgcn_mfma_f32_16x16x32_bf16(
                qfrag, kf[b], (f32x4){CINIT, CINIT, CINIT, CINIT}, 0, 0, 0);

        // prefetch next tile's K fragments (redundant reload on last iter)
        const int ktn = (kt + 1 < kt_end) ? kt + 1 : kt;
#pragma unroll
        for (int b = 0; b < 4; ++b)
            kf[b] = *(const bf16x8*)&K[((ktn << 6) + b * 16 + lcol) * HD + grp * 8];

        // V^T fragments (latency hidden behind softmax)
        bf16x8 vf[4];
#pragma unroll
        for (int c = 0; c < 2; ++c) {
            vf[c * 2 + 0] = *(const bf16x8*)&Vt[(c * 16 + lcol) * NTOK + k0 + grp * 8];
            vf[c * 2 + 1] = *(const bf16x8*)&Vt[(c * 16 + lcol) * NTOK + k0 + 32 + grp * 8];
        }

        // p = exp2(s') masked; round-half-up to bf16; wave-private P rows
#pragma unroll
        for (int j = 0; j < 4; ++j) {
            const u64x4 wj = (j == 0) ? w0 : (j == 1) ? w1 : (j == 2) ? w2 : w3;
            float p0 = sel_mask(exp2_fast(s[0][j]), wj[0]);
            float p1 = sel_mask(exp2_fast(s[1][j]), wj[1]);
            float p2 = sel_mask(exp2_fast(s[2][j]), wj[2]);
            float p3 = sel_mask(exp2_fast(s[3][j]), wj[3]);
            lsum[j] += (p0 + p1) + (p2 + p3);
            const int prow = wv * 16 + grp * 4 + j;
            P_lds[prow][lcol]      = (short)f2bf_fast(p0);
            P_lds[prow][16 + lcol] = (short)f2bf_fast(p1);
            P_lds[prow][32 + lcol] = (short)f2bf_fast(p2);
            P_lds[prow][48 + lcol] = (short)f2bf_fast(p3);
        }

        const bf16x8 pf0 = *(const bf16x8*)&P_lds[wv * 16 + lcol][grp * 8];
        const bf16x8 pf1 = *(const bf16x8*)&P_lds[wv * 16 + lcol][32 + grp * 8];
#pragma unroll
        for (int c = 0; c < 2; ++c) {
            o[c] = __builtin_amdgcn_mfma_f32_16x16x32_bf16(pf0, vf[c * 2 + 0], o[c], 0, 0, 0);
            o[c] = __builtin_amdgcn_mfma_f32_16x16x32_bf16(pf1, vf[c * 2 + 1], o[c], 0, 0, 0);
        }
    }

#pragma unroll
    for (int j = 0; j < 4; ++j) {
        float v = lsum[j];
        v += __shfl_xor(v, 1); v += __shfl_xor(v, 2);
        v += __shfl_xor(v, 4); v += __shfl_xor(v, 8);
        lsum[j] = v;
    }

    float* __restrict__ ob = o_part + split * (NTOK * EDIM);
#pragma unroll
    for (int c = 0; c < 2; ++c)
#pragma unroll
        for (int j = 0; j < 4; ++j)
            ob[(qrow_base + j) * EDIM + h * HD + c * 16 + lcol] = o[c][j];
    if (lcol == 0) {
#pragma unroll
        for (int j = 0; j < 4; ++j)
            l_part[split * (NTOK * HEADS) + (qrow_base + j) * HEADS + h] = lsum[j];
    }
}

// ---- split-K combine + normalize + bf16 cast: ab[tok][feat] --------------
__global__ __launch_bounds__(256) void combine_cast(
    const float* __restrict__ o_part, const float* __restrict__ l_part,
    short* __restrict__ ab)
{
    const int gid = blockIdx.x * 256 + threadIdx.x;
    const int row = gid >> 6;
    const int c4 = (gid & 63) << 2;
    const int hh = c4 >> 5;
    float4 a0 = *(const float4*)&o_part[0 * (NTOK * EDIM) + row * EDIM + c4];
    float4 a1 = *(const float4*)&o_part[1 * (NTOK * EDIM) + row * EDIM + c4];
    float4 a2 = *(const float4*)&o_part[2 * (NTOK * EDIM) + row * EDIM + c4];
    float4 a3 = *(const float4*)&o_part[3 * (NTOK * EDIM) + row * EDIM + c4];
    const float l = l_part[0 * (NTOK * HEADS) + row * HEADS + hh]
                  + l_part[1 * (NTOK * HEADS) + row * HEADS + hh]
                  + l_part[2 * (NTOK * HEADS) + row * HEADS + hh]
                  + l_part[3 * (NTOK * HEADS) + row * HEADS + hh];
    const float inv = 1.0f / l;
    const float r0 = (a0.x + a1.x + a2.x + a3.x) * inv;
    const float r1 = (a0.y + a1.y + a2.y + a3.y) * inv;
    const float r2 = (a0.z + a1.z + a2.z + a3.z) * inv;
    const float r3 = (a0.w + a1.w + a2.w + a3.w) * inv;
    uint2 t;
    t.x = (unsigned short)f2bf(r0) | ((unsigned)(unsigned short)f2bf(r1) << 16);
    t.y = (unsigned short)f2bf(r2) | ((unsigned)(unsigned short)f2bf(r3) << 16);
    *(uint2*)&ab[row * EDIM + c4] = t;
}

// ---- output projection via MFMA: Y = ab @ Wo^T + bo (fp32 out) -----------
__global__ __launch_bounds__(256) void out_mfma(
    const short* __restrict__ ab, const short* __restrict__ Wob,
    const float* __restrict__ bo, float* __restrict__ Y)
{
    const int tid = threadIdx.x;
    const int wv = tid >> 6, lane = tid & 63;
    const int grp = lane >> 4, lcol = lane & 15;
    const int n0 = blockIdx.y << 4;
    const int m0 = blockIdx.x * 64 + wv * 16;

    f32x4 acc = {};
#pragma unroll
    for (int k = 0; k < 8; ++k) {
        const bf16x8 a = *(const bf16x8*)&ab[(m0 + lcol) * 256 + k * 32 + grp * 8];
        const bf16x8 b = *(const bf16x8*)&Wob[(n0 + lcol) * 256 + k * 32 + grp * 8];
        acc = __builtin_amdgcn_mfma_f32_16x16x32_bf16(a, b, acc, 0, 0, 0);
    }
    const float bval = bo[n0 + lcol];
#pragma unroll
    for (int j = 0; j < 4; ++j)
        Y[(m0 + grp * 4 + j) * EDIM + n0 + lcol] = acc[j] + bval;
}

extern "C" void kernel_launch(void* const* d_in, const int* in_sizes, int n_in,
                              void* d_out, int out_size, void* d_ws, size_t ws_size,
                              hipStream_t stream) {
    (void)in_sizes; (void)n_in; (void)out_size; (void)ws_size;
    const float* x  = (const float*)d_in[0];
    const int*  adj = (const int*)d_in[1];
    const float* Wq = (const float*)d_in[2];
    const float* bq = (const float*)d_in[3];
    const float* Wk = (const float*)d_in[4];
    const float* bk = (const float*)d_in[5];
    const float* Wv = (const float*)d_in[6];
    const float* bv = (const float*)d_in[7];
    const float* Wo = (const float*)d_in[8];
    const float* bo = (const float*)d_in[9];

    char* ws = (char*)d_ws;
    short* x_bf  = (short*)(ws);                        // 2 MB  [N][256]
    short* q_ws  = (short*)(ws + (2u << 20));           // 2 MB  [H][N][32]
    short* k_ws  = (short*)(ws + (4u << 20));           // 2 MB
    short* vt_ws = (short*)(ws + (6u << 20));           // 2 MB  [H][32][N]
    unsigned long long* maskC =
        (unsigned long long*)(ws + (8u << 20));         // 2 MB
    short* a_bf  = (short*)(ws + (10u << 20));          // 2 MB  [N][256]
    short* Wq_bf = (short*)(ws + (12u << 20));          // 128 KB each
    short* Wk_bf = Wq_bf + (EDIM * EDIM);
    short* Wv_bf = Wk_bf + (EDIM * EDIM);
    short* Wo_bf = Wv_bf + (EDIM * EDIM);
    float* l_part = (float*)(ws + (13u << 20));         // 512 KB [4][N][8]
    float* o_part = (float*)(ws + (16u << 20));         // 16 MB  [4][N][256]

    pack_mask<<<dim3(65536), 256, 0, stream>>>(adj, maskC);
    cast_bf<<<dim3(1024), 256, 0, stream>>>(x, x_bf, (NTOK * EDIM) / 4);
    cast_bf<<<dim3(64), 256, 0, stream>>>(Wq, Wq_bf, (EDIM * EDIM) / 4);
    cast_bf<<<dim3(64), 256, 0, stream>>>(Wk, Wk_bf, (EDIM * EDIM) / 4);
    cast_bf<<<dim3(64), 256, 0, stream>>>(Wv, Wv_bf, (EDIM * EDIM) / 4);
    cast_bf<<<dim3(64), 256, 0, stream>>>(Wo, Wo_bf, (EDIM * EDIM) / 4);
    qkv_mfma<<<dim3(64, 48), 256, 0, stream>>>(x_bf, Wq_bf, Wk_bf, Wv_bf,
                                               bq, bk, bv, q_ws, k_ws, vt_ws);
    attn_mfma<<<dim3(64, HEADS, NSPLIT), 256, 0, stream>>>(
        q_ws, k_ws, vt_ws, maskC, o_part, l_part);
    combine_cast<<<dim3(1024), 256, 0, stream>>>(o_part, l_part, a_bf);
    out_mfma<<<dim3(64, 16), 256, 0, stream>>>(a_bf, Wo_bf, bo, (float*)d_out);
}

// Round 5
// 232.710 us; speedup vs baseline: 3.2673x; 1.1285x over previous
//
#include <hip/hip_runtime.h>
#include <math.h>

// GraphAttentionBlock: B=1, N=4096, E=256, H=8, D=32, fp32 in/out.
// R5: attn computes S^T/O^T (swapped MFMA operands) so the P C->A transform
// is 4x ds_write_b64 + 4x ds_read_b64 per tile (was 16 u16 writes + 2 b128
// reads); mask repacked to S^T order -> 16 contiguous u64 scalar loads/tile;
// O stores vectorized (float4x2). Casts merged to one kernel; qkv/out GEMMs
// use 16x64 per-wave tiles (32 MFMA per wave).

#define NTOK 4096
#define EDIM 256
#define HEADS 8
#define HD 32
#define NSPLIT 4
#define QSCALE 0.17677669529663687f            // 1/sqrt(32)
#define LOG2E 1.4426950408889634f
#define CINIT (-11.541560327111707f)           // -8 * log2(e)

typedef __attribute__((ext_vector_type(8))) short bf16x8;
typedef __attribute__((ext_vector_type(4))) float f32x4;
typedef __attribute__((ext_vector_type(4))) unsigned long long u64x4;

static __device__ inline short f2bf(float f) {          // RNE
    unsigned u = __float_as_uint(f);
    u = (u + 0x7FFFu + ((u >> 16) & 1u)) >> 16;
    return (short)u;
}
// pack two floats to bf16x2 (round-half-up; errors cancel in O/l ratio)
static __device__ inline unsigned pack2bf(float a, float b) {
    unsigned pa = __float_as_uint(a) + 0x8000u;
    unsigned pb = __float_as_uint(b) + 0x8000u;
    return (pa >> 16) | (pb & 0xFFFF0000u);
}
static __device__ inline float exp2_fast(float x) {
    float r;
    asm("v_exp_f32 %0, %1" : "=v"(r) : "v"(x));
    return r;
}
// p = (mask bit for this lane) ? v : 0   -- one VALU op, sgpr-pair mask
static __device__ inline float sel_mask(float v, unsigned long long m) {
    float r;
    asm("v_cndmask_b32 %0, 0, %1, %2" : "=v"(r) : "v"(v), "s"(m));
    return r;
}

// ---- adjacency -> S^T-order bitmask --------------------------------------
// word(qb,kt,b,j) at maskT[qb*1024+kt*16+b*4+j]:
//   bit l = adj[qb*16 + (l&15)][kt*64 + b*16 + ((l>>4)&3)*4 + j]
__global__ __launch_bounds__(256) void pack_mask(
    const int* __restrict__ adj, unsigned long long* __restrict__ maskT)
{
    const int w = blockIdx.x * 4 + (threadIdx.x >> 6);  // (qb,kt,b)
    const int l = threadIdx.x & 63;
    const int qb = w >> 8;
    const int kt = (w >> 2) & 63;
    const int b = w & 3;
    const int row = qb * 16 + (l & 15);
    const int col = kt * 64 + b * 16 + ((l >> 4) & 3) * 4;
    const int4 av = *(const int4*)&adj[row * NTOK + col];
    const unsigned long long m0 = __ballot(av.x != 0);
    const unsigned long long m1 = __ballot(av.y != 0);
    const unsigned long long m2 = __ballot(av.z != 0);
    const unsigned long long m3 = __ballot(av.w != 0);
    if (l == 0) {
        unsigned long long* dst = &maskT[(size_t)w * 4];
        dst[0] = m0; dst[1] = m1; dst[2] = m2; dst[3] = m3;
    }
}

// ---- one-shot fp32 -> bf16 cast of x and the 4 weight matrices -----------
__global__ __launch_bounds__(256) void cast_all(
    const float* __restrict__ x,  const float* __restrict__ Wq,
    const float* __restrict__ Wk, const float* __restrict__ Wv,
    const float* __restrict__ Wo,
    short* __restrict__ xb,  short* __restrict__ wqb,
    short* __restrict__ wkb, short* __restrict__ wvb,
    short* __restrict__ wob)
{
    const int gid = blockIdx.x * 256 + threadIdx.x;
    const int e = gid * 4;
    const float* src; short* dst; int off;
    if (e < NTOK * EDIM) { src = x; dst = xb; off = e; }
    else {
        const int r = e - NTOK * EDIM;
        const int wsel = r >> 16;
        off = r & 65535;
        src = (wsel == 0) ? Wq : (wsel == 1) ? Wk : (wsel == 2) ? Wv : Wo;
        dst = (wsel == 0) ? wqb : (wsel == 1) ? wkb : (wsel == 2) ? wvb : wob;
    }
    float4 v = *(const float4*)&src[off];
    uint2 t;
    t.x = (unsigned short)f2bf(v.x) | ((unsigned)(unsigned short)f2bf(v.y) << 16);
    t.y = (unsigned short)f2bf(v.z) | ((unsigned)(unsigned short)f2bf(v.w) << 16);
    *(uint2*)&dst[off] = t;
}

// ---- QKV projection via MFMA, 16x64 per wave; q/k head-major, v transposed
__global__ __launch_bounds__(256) void qkv_mfma(
    const short* __restrict__ xb,
    const short* __restrict__ Wqb, const short* __restrict__ Wkb,
    const short* __restrict__ Wvb,
    const float* __restrict__ bq, const float* __restrict__ bk,
    const float* __restrict__ bv,
    short* __restrict__ qo, short* __restrict__ ko, short* __restrict__ vto)
{
    const int tid = threadIdx.x;
    const int wv = tid >> 6, lane = tid & 63;
    const int grp = lane >> 4, lcol = lane & 15;
    const int wsel = blockIdx.y >> 2;                  // 0=Q 1=K 2=V
    const int n0 = (blockIdx.y & 3) << 6;
    const int m0 = blockIdx.x * 64 + wv * 16;
    const short* __restrict__ W = (wsel == 0) ? Wqb : (wsel == 1) ? Wkb : Wvb;
    const float* __restrict__ bias = (wsel == 0) ? bq : (wsel == 1) ? bk : bv;

    f32x4 acc[4] = {};
#pragma unroll
    for (int k = 0; k < 8; ++k) {
        const bf16x8 a = *(const bf16x8*)&xb[(m0 + lcol) * 256 + k * 32 + grp * 8];
#pragma unroll
        for (int t = 0; t < 4; ++t) {
            const bf16x8 bt =
                *(const bf16x8*)&W[(n0 + t * 16 + lcol) * 256 + k * 32 + grp * 8];
            acc[t] = __builtin_amdgcn_mfma_f32_16x16x32_bf16(a, bt, acc[t], 0, 0, 0);
        }
    }
#pragma unroll
    for (int t = 0; t < 4; ++t) {
        const int feat = n0 + t * 16 + lcol;
        const float bval = bias[feat];
        const int h = feat >> 5, d = feat & 31;
        if (wsel == 2) {
            // vt[h][d][tok], tokens m0+grp*4+j consecutive -> one 8B store
            uint2 o;
            o.x = (unsigned short)f2bf(acc[t][0] + bval) |
                  ((unsigned)(unsigned short)f2bf(acc[t][1] + bval) << 16);
            o.y = (unsigned short)f2bf(acc[t][2] + bval) |
                  ((unsigned)(unsigned short)f2bf(acc[t][3] + bval) << 16);
            *(uint2*)&vto[h * (HD * NTOK) + d * NTOK + m0 + grp * 4] = o;
        } else {
            short* __restrict__ out = (wsel == 0) ? qo : ko;
            const float sc = (wsel == 0) ? (QSCALE * LOG2E) : 1.0f;
#pragma unroll
            for (int j = 0; j < 4; ++j)
                out[h * (NTOK * HD) + (m0 + grp * 4 + j) * HD + d] =
                    f2bf((acc[t][j] + bval) * sc);
        }
    }
}

// ---- barrier-free MFMA flash attention (S^T / O^T form) ------------------
__global__ __launch_bounds__(256) void attn_mfma(
    const short* __restrict__ qg, const short* __restrict__ kg,
    const short* __restrict__ vtg, const unsigned long long* __restrict__ maskT,
    float* __restrict__ o_part, float* __restrict__ l_part)
{
    const int h = blockIdx.y;
    const int split = blockIdx.z;
    const int q0 = blockIdx.x << 6;
    const short* __restrict__ Q  = qg  + h * (NTOK * HD);
    const short* __restrict__ K  = kg  + h * (NTOK * HD);
    const short* __restrict__ Vt = vtg + h * (HD * NTOK);

    // per-wave P^T tile: [qrow 16][key 64 + pad 12] -> 152B rows (uniform
    // 4-way banking on b64 ops = optimal for 128 bank-accesses)
    __shared__ short P_lds[4][16][76];

    const int tid = threadIdx.x;
    const int wv = tid >> 6;
    const int lane = tid & 63;
    const int grp = lane >> 4;
    const int lcol = lane & 15;
    const int q0w = q0 + wv * 16;

    // Q as B-operand: B[n=lcol(qrow)][k=grp*8+j(d)]
    const bf16x8 qfrag = *(const bf16x8*)&Q[(q0w + lcol) * HD + grp * 8];

    const int qb = __builtin_amdgcn_readfirstlane(blockIdx.x * 4 + wv);
    const unsigned long long* __restrict__ mbase = maskT + (size_t)qb * 1024;

    f32x4 ot[2] = {};     // O^T C-layout: row=grp*4+j (d), col=lcol (qrow)
    float lsum = 0.f;

    const int kt_begin = split * (64 / NSPLIT);
    const int kt_end = kt_begin + (64 / NSPLIT);

    bf16x8 kf[4];
#pragma unroll
    for (int b = 0; b < 4; ++b)
        kf[b] = *(const bf16x8*)&K[((kt_begin << 6) + b * 16 + lcol) * HD + grp * 8];

    for (int kt = kt_begin; kt < kt_end; ++kt) {
        const int k0 = kt << 6;
        const u64x4* mp = (const u64x4*)(mbase + kt * 16);
        const u64x4 wa = mp[0], wb = mp[1], wc = mp[2], wd = mp[3];

        // S^T = K Q^T (scaled, minus 8*log2e): row=key_in_blk, col=qrow
        f32x4 s[4];
#pragma unroll
        for (int b = 0; b < 4; ++b)
            s[b] = __builtin_amdgcn_mfma_f32_16x16x32_bf16(
                kf[b], qfrag, (f32x4){CINIT, CINIT, CINIT, CINIT}, 0, 0, 0);

        // prefetch next tile's K fragments
        const int ktn = (kt + 1 < kt_end) ? kt + 1 : kt;
#pragma unroll
        for (int b = 0; b < 4; ++b)
            kf[b] = *(const bf16x8*)&K[((ktn << 6) + b * 16 + lcol) * HD + grp * 8];

        // V^T fragments (A-operand of O^T): A[m=lcol(d)][k=grp*8+j(key)]
        bf16x8 vf[4];
#pragma unroll
        for (int c = 0; c < 2; ++c) {
            vf[c * 2 + 0] = *(const bf16x8*)&Vt[(c * 16 + lcol) * NTOK + k0 + grp * 8];
            vf[c * 2 + 1] = *(const bf16x8*)&Vt[(c * 16 + lcol) * NTOK + k0 + 32 + grp * 8];
        }

        // p = exp2(s') masked; pack j=0..3 (consecutive keys) -> ds_write_b64
#pragma unroll
        for (int b = 0; b < 4; ++b) {
            const u64x4 wj = (b == 0) ? wa : (b == 1) ? wb : (b == 2) ? wc : wd;
            const float p0 = sel_mask(exp2_fast(s[b][0]), wj[0]);
            const float p1 = sel_mask(exp2_fast(s[b][1]), wj[1]);
            const float p2 = sel_mask(exp2_fast(s[b][2]), wj[2]);
            const float p3 = sel_mask(exp2_fast(s[b][3]), wj[3]);
            lsum += (p0 + p1) + (p2 + p3);
            uint2 t;
            t.x = pack2bf(p0, p1);
            t.y = pack2bf(p2, p3);
            *(uint2*)&P_lds[wv][lcol][b * 16 + grp * 4] = t;
        }

        // P as B-operand: B[n=lcol(qrow)][k=grp*8+j(key)] -> row-contiguous
        const uint2 pl0 = *(const uint2*)&P_lds[wv][lcol][grp * 8];
        const uint2 pl1 = *(const uint2*)&P_lds[wv][lcol][grp * 8 + 4];
        const uint2 pl2 = *(const uint2*)&P_lds[wv][lcol][32 + grp * 8];
        const uint2 pl3 = *(const uint2*)&P_lds[wv][lcol][32 + grp * 8 + 4];
        struct { uint2 a, b; } u0 = {pl0, pl1}, u1 = {pl2, pl3};
        const bf16x8 pf0 = __builtin_bit_cast(bf16x8, u0);
        const bf16x8 pf1 = __builtin_bit_cast(bf16x8, u1);

#pragma unroll
        for (int c = 0; c < 2; ++c) {
            ot[c] = __builtin_amdgcn_mfma_f32_16x16x32_bf16(vf[c * 2 + 0], pf0, ot[c], 0, 0, 0);
            ot[c] = __builtin_amdgcn_mfma_f32_16x16x32_bf16(vf[c * 2 + 1], pf1, ot[c], 0, 0, 0);
        }
    }

    // l: sum over the 4 lane-groups holding this qrow's keys
    lsum += __shfl_xor(lsum, 16);
    lsum += __shfl_xor(lsum, 32);

    float* __restrict__ ob = o_part + split * (NTOK * EDIM);
#pragma unroll
    for (int c = 0; c < 2; ++c) {
        float4 st;
        st.x = ot[c][0]; st.y = ot[c][1]; st.z = ot[c][2]; st.w = ot[c][3];
        *(float4*)&ob[(q0w + lcol) * EDIM + h * HD + c * 16 + grp * 4] = st;
    }
    if (grp == 0)
        l_part[split * (NTOK * HEADS) + (q0w + lcol) * HEADS + h] = lsum;
}

// ---- split-K combine + normalize + bf16 cast -----------------------------
__global__ __launch_bounds__(256) void combine_cast(
    const float* __restrict__ o_part, const float* __restrict__ l_part,
    short* __restrict__ ab)
{
    const int gid = blockIdx.x * 256 + threadIdx.x;
    const int row = gid >> 6;
    const int c4 = (gid & 63) << 2;
    const int hh = c4 >> 5;
    float4 a0 = *(const float4*)&o_part[0 * (NTOK * EDIM) + row * EDIM + c4];
    float4 a1 = *(const float4*)&o_part[1 * (NTOK * EDIM) + row * EDIM + c4];
    float4 a2 = *(const float4*)&o_part[2 * (NTOK * EDIM) + row * EDIM + c4];
    float4 a3 = *(const float4*)&o_part[3 * (NTOK * EDIM) + row * EDIM + c4];
    const float l = l_part[0 * (NTOK * HEADS) + row * HEADS + hh]
                  + l_part[1 * (NTOK * HEADS) + row * HEADS + hh]
                  + l_part[2 * (NTOK * HEADS) + row * HEADS + hh]
                  + l_part[3 * (NTOK * HEADS) + row * HEADS + hh];
    const float inv = 1.0f / l;
    const float r0 = (a0.x + a1.x + a2.x + a3.x) * inv;
    const float r1 = (a0.y + a1.y + a2.y + a3.y) * inv;
    const float r2 = (a0.z + a1.z + a2.z + a3.z) * inv;
    const float r3 = (a0.w + a1.w + a2.w + a3.w) * inv;
    uint2 t;
    t.x = (unsigned short)f2bf(r0) | ((unsigned)(unsigned short)f2bf(r1) << 16);
    t.y = (unsigned short)f2bf(r2) | ((unsigned)(unsigned short)f2bf(r3) << 16);
    *(uint2*)&ab[row * EDIM + c4] = t;
}

// ---- output projection via MFMA, 16x64 per wave --------------------------
__global__ __launch_bounds__(256) void out_mfma(
    const short* __restrict__ ab, const short* __restrict__ Wob,
    const float* __restrict__ bo, float* __restrict__ Y)
{
    const int tid = threadIdx.x;
    const int wv = tid >> 6, lane = tid & 63;
    const int grp = lane >> 4, lcol = lane & 15;
    const int n0 = blockIdx.y << 6;
    const int m0 = blockIdx.x * 64 + wv * 16;

    f32x4 acc[4] = {};
#pragma unroll
    for (int k = 0; k < 8; ++k) {
        const bf16x8 a = *(const bf16x8*)&ab[(m0 + lcol) * 256 + k * 32 + grp * 8];
#pragma unroll
        for (int t = 0; t < 4; ++t) {
            const bf16x8 bt =
                *(const bf16x8*)&Wob[(n0 + t * 16 + lcol) * 256 + k * 32 + grp * 8];
            acc[t] = __builtin_amdgcn_mfma_f32_16x16x32_bf16(a, bt, acc[t], 0, 0, 0);
        }
    }
#pragma unroll
    for (int t = 0; t < 4; ++t) {
        const float bval = bo[n0 + t * 16 + lcol];
#pragma unroll
        for (int j = 0; j < 4; ++j)
            Y[(m0 + grp * 4 + j) * EDIM + n0 + t * 16 + lcol] = acc[t][j] + bval;
    }
}

extern "C" void kernel_launch(void* const* d_in, const int* in_sizes, int n_in,
                              void* d_out, int out_size, void* d_ws, size_t ws_size,
                              hipStream_t stream) {
    (void)in_sizes; (void)n_in; (void)out_size; (void)ws_size;
    const float* x  = (const float*)d_in[0];
    const int*  adj = (const int*)d_in[1];
    const float* Wq = (const float*)d_in[2];
    const float* bq = (const float*)d_in[3];
    const float* Wk = (const float*)d_in[4];
    const float* bk = (const float*)d_in[5];
    const float* Wv = (const float*)d_in[6];
    const float* bv = (const float*)d_in[7];
    const float* Wo = (const float*)d_in[8];
    const float* bo = (const float*)d_in[9];

    char* ws = (char*)d_ws;
    short* x_bf  = (short*)(ws);                        // 2 MB  [N][256]
    short* q_ws  = (short*)(ws + (2u << 20));           // 2 MB  [H][N][32]
    short* k_ws  = (short*)(ws + (4u << 20));           // 2 MB
    short* vt_ws = (short*)(ws + (6u << 20));           // 2 MB  [H][32][N]
    unsigned long long* maskT =
        (unsigned long long*)(ws + (8u << 20));         // 2 MB
    short* a_bf  = (short*)(ws + (10u << 20));          // 2 MB  [N][256]
    short* Wq_bf = (short*)(ws + (12u << 20));          // 128 KB each
    short* Wk_bf = Wq_bf + (EDIM * EDIM);
    short* Wv_bf = Wk_bf + (EDIM * EDIM);
    short* Wo_bf = Wv_bf + (EDIM * EDIM);
    float* l_part = (float*)(ws + (13u << 20));         // 512 KB [4][N][8]
    float* o_part = (float*)(ws + (16u << 20));         // 16 MB  [4][N][256]

    pack_mask<<<dim3(16384), 256, 0, stream>>>(adj, maskT);
    cast_all<<<dim3(1280), 256, 0, stream>>>(x, Wq, Wk, Wv, Wo,
                                             x_bf, Wq_bf, Wk_bf, Wv_bf, Wo_bf);
    qkv_mfma<<<dim3(64, 12), 256, 0, stream>>>(x_bf, Wq_bf, Wk_bf, Wv_bf,
                                               bq, bk, bv, q_ws, k_ws, vt_ws);
    attn_mfma<<<dim3(64, HEADS, NSPLIT), 256, 0, stream>>>(
        q_ws, k_ws, vt_ws, maskT, o_part, l_part);
    combine_cast<<<dim3(1024), 256, 0, stream>>>(o_part, l_part, a_bf);
    out_mfma<<<dim3(64, 4), 256, 0, stream>>>(a_bf, Wo_bf, bo, (float*)d_out);
}